// Round 5
// baseline (478.486 us; speedup 1.0000x reference)
//
#include <hip/hip_runtime.h>
#include <cstdint>
#include <cstddef>

// Problem constants: B=4, T=2048, C=1024, H=16, d=64
#define T_SEQ 2048
#define CEMB  1024
#define NHEAD 16
#define DHEAD 64

// q pre-scale: 32 (sqrt(C) quirk) * log2(e)  -> logits in log2 units
#define QSCALE 46.1662413084468f

typedef __attribute__((ext_vector_type(8))) short bf16x8;
typedef __attribute__((ext_vector_type(4))) float f32x4;

static __device__ __forceinline__ unsigned short f2bf(float x) {
    unsigned u = __builtin_bit_cast(unsigned, x);
    unsigned r = (u + 0x7FFFu + ((u >> 16) & 1u)) >> 16;
    return (unsigned short)r;
}
static __device__ __forceinline__ float bf2f(unsigned short b) {
    unsigned u = ((unsigned)b) << 16;
    return __builtin_bit_cast(float, u);
}

// async global->LDS: 16B per lane; ldsbase wave-uniform, lane offset = lane*16B.
static __device__ __forceinline__ void gload16(const short* gsrc, short* ldsbase) {
    __builtin_amdgcn_global_load_lds(
        (const __attribute__((address_space(1))) void*)gsrc,
        (__attribute__((address_space(3))) void*)ldsbase, 16, 0, 0);
}

// ---------------------------------------------------------------------------
// MFMA GEMM, 128x128 tile, BK=32, 256 threads (4 waves, 2x2).
//   C[M][N] = A[M][K] @ B^T[N][K]^T + bias[N]
// SPLIT==3: A,B split hi/lo bf16, 3 MFMAs (hh+lh+hl) -> ~fp32 product.
// A_F32: A read fp32, split in staging. Else A bf16 via global_load_lds.
// OUT_MODE: 0 = fp32, 1 = bf16, 2 = split hi/lo bf16 (cols<1024 scaled QSCALE).
// ---------------------------------------------------------------------------
template<int SPLIT, bool A_F32, int OUT_MODE>
__global__ __launch_bounds__(256) void gemm_mfma_kernel(
    const float* __restrict__ Af, const short* __restrict__ Ah,
    const short* __restrict__ Bh, const short* __restrict__ Bl,
    const float* __restrict__ bias,
    void* __restrict__ Cout, void* __restrict__ Cout2, int K, int ldc)
{
    __shared__ __align__(16) short smem[(SPLIT == 3) ? 16384 : 8192];

    const int tid = threadIdx.x;
    const int w = tid >> 6, l = tid & 63;
    const int lr = l & 15, lg = l >> 4;
    const int wr = w >> 1, wc = w & 1;
    const int row0 = blockIdx.y * 128;
    const int col0 = blockIdx.x * 128;

    f32x4 acc[4][4];
    #pragma unroll
    for (int mt = 0; mt < 4; ++mt)
        #pragma unroll
        for (int nt = 0; nt < 4; ++nt)
            acc[mt][nt] = (f32x4){0.f, 0.f, 0.f, 0.f};

    const int sB0 = w * 128 + l, sB1 = sB0 + 64;
    const short* gB0 = Bh + (size_t)(col0 + (sB0 & 127)) * K + (sB0 >> 7) * 8;
    const short* gB1 = Bh + (size_t)(col0 + (sB1 & 127)) * K + (sB1 >> 7) * 8;
    short* dB0 = &smem[4096 + (w * 128) * 8];
    short* dB1 = &smem[4096 + (w * 128 + 64) * 8];
    const short* gBl0 = nullptr; const short* gBl1 = nullptr;
    if constexpr (SPLIT == 3) {
        gBl0 = Bl + (size_t)(col0 + (sB0 & 127)) * K + (sB0 >> 7) * 8;
        gBl1 = Bl + (size_t)(col0 + (sB1 & 127)) * K + (sB1 >> 7) * 8;
    }
    const short* gA0 = nullptr; const short* gA1 = nullptr;
    if constexpr (!A_F32) {
        gA0 = Ah + (size_t)(row0 + (sB0 & 127)) * K + (sB0 >> 7) * 8;
        gA1 = Ah + (size_t)(row0 + (sB1 & 127)) * K + (sB1 >> 7) * 8;
    }
    short* dA0 = &smem[(w * 128) * 8];
    short* dA1 = &smem[(w * 128 + 64) * 8];

    const int arow = tid >> 1, ahalf = tid & 1;
    const float* gAf = A_F32 ? (Af + (size_t)(row0 + arow) * K + ahalf * 16) : nullptr;

    for (int kt = 0; kt < K; kt += 32) {
        __syncthreads();
        if constexpr (!A_F32) {
            gload16(gA0 + kt, dA0);
            gload16(gA1 + kt, dA1);
        }
        gload16(gB0 + kt, dB0);
        gload16(gB1 + kt, dB1);
        if constexpr (SPLIT == 3) {
            gload16(gBl0 + kt, &smem[12288 + (w * 128) * 8]);
            gload16(gBl1 + kt, &smem[12288 + (w * 128 + 64) * 8]);
        }
        if constexpr (A_F32) {
            const float* src = gAf + kt;
            float4 f0 = *(const float4*)(src);
            float4 f1 = *(const float4*)(src + 4);
            float4 f2 = *(const float4*)(src + 8);
            float4 f3 = *(const float4*)(src + 12);
            float xs[16] = {f0.x, f0.y, f0.z, f0.w, f1.x, f1.y, f1.z, f1.w,
                            f2.x, f2.y, f2.z, f2.w, f3.x, f3.y, f3.z, f3.w};
            #pragma unroll
            for (int q = 0; q < 2; ++q) {
                bf16x8 h8, l8;
                #pragma unroll
                for (int e = 0; e < 8; ++e) {
                    float x = xs[q * 8 + e];
                    if constexpr (SPLIT == 3) {
                        unsigned u = __builtin_bit_cast(unsigned, x);
                        h8[e] = (short)(unsigned short)(u >> 16);
                        float hf = __builtin_bit_cast(float, u & 0xFFFF0000u);
                        l8[e] = (short)f2bf(x - hf);
                    } else {
                        h8[e] = (short)f2bf(x);
                    }
                }
                int slot = (ahalf * 2 + q) * 128 + arow;
                *(bf16x8*)&smem[slot * 8] = h8;
                if constexpr (SPLIT == 3) *(bf16x8*)&smem[8192 + slot * 8] = l8;
            }
        }
        __syncthreads();

        const int aoff = (lg * 128 + wr * 64 + lr) * 8;
        const int boff = 4096 + (lg * 128 + wc * 64 + lr) * 8;
        bf16x8 ahf[4], alf[4];
        #pragma unroll
        for (int mt = 0; mt < 4; ++mt) {
            ahf[mt] = *(const bf16x8*)&smem[aoff + mt * 128];
            if constexpr (SPLIT == 3)
                alf[mt] = *(const bf16x8*)&smem[8192 + aoff + mt * 128];
        }
        #pragma unroll
        for (int nt = 0; nt < 4; ++nt) {
            bf16x8 bhf = *(const bf16x8*)&smem[boff + nt * 128];
            if constexpr (SPLIT == 3) {
                bf16x8 blf = *(const bf16x8*)&smem[8192 + boff + nt * 128];
                #pragma unroll
                for (int mt = 0; mt < 4; ++mt) {
                    acc[mt][nt] = __builtin_amdgcn_mfma_f32_16x16x32_bf16(ahf[mt], bhf, acc[mt][nt], 0, 0, 0);
                    acc[mt][nt] = __builtin_amdgcn_mfma_f32_16x16x32_bf16(alf[mt], bhf, acc[mt][nt], 0, 0, 0);
                    acc[mt][nt] = __builtin_amdgcn_mfma_f32_16x16x32_bf16(ahf[mt], blf, acc[mt][nt], 0, 0, 0);
                }
            } else {
                #pragma unroll
                for (int mt = 0; mt < 4; ++mt)
                    acc[mt][nt] = __builtin_amdgcn_mfma_f32_16x16x32_bf16(ahf[mt], bhf, acc[mt][nt], 0, 0, 0);
            }
        }
    }

    #pragma unroll
    for (int mt = 0; mt < 4; ++mt) {
        #pragma unroll
        for (int r = 0; r < 4; ++r) {
            int m = row0 + wr * 64 + mt * 16 + lg * 4 + r;
            #pragma unroll
            for (int nt = 0; nt < 4; ++nt) {
                int n = col0 + wc * 64 + nt * 16 + lr;
                float v = acc[mt][nt][r] + bias[n];
                if constexpr (OUT_MODE == 0) {
                    ((float*)Cout)[(size_t)m * ldc + n] = v;
                } else if constexpr (OUT_MODE == 1) {
                    ((short*)Cout)[(size_t)m * ldc + n] = (short)f2bf(v);
                } else {
                    if (n < 1024) v *= QSCALE;
                    unsigned u = __builtin_bit_cast(unsigned, v);
                    ((short*)Cout)[(size_t)m * ldc + n] = (short)(unsigned short)(u >> 16);
                    float hf = __builtin_bit_cast(float, u & 0xFFFF0000u);
                    ((short*)Cout2)[(size_t)m * ldc + n] = (short)f2bf(v - hf);
                }
            }
        }
    }
}

// ---------------------------------------------------------------------------
// Transpose + hi/lo bf16 split: src fp32 [Krows][nsrc] -> hi/lo [N][1024]
// ---------------------------------------------------------------------------
__global__ __launch_bounds__(256) void transpose_split_kernel(
    const float* __restrict__ src, int nsrc,
    short* __restrict__ hi, short* __restrict__ lo)
{
    __shared__ float tile[64][68];
    const int tid = threadIdx.x;
    const int n0 = blockIdx.x * 64, k0 = blockIdx.y * 64;
    {
        int kr = tid >> 2, cg = tid & 3;
        const float* s = src + (size_t)(k0 + kr) * nsrc + n0 + cg * 16;
        #pragma unroll
        for (int q = 0; q < 4; ++q) {
            float4 f = *(const float4*)(s + q * 4);
            tile[kr][cg * 16 + q * 4 + 0] = f.x;
            tile[kr][cg * 16 + q * 4 + 1] = f.y;
            tile[kr][cg * 16 + q * 4 + 2] = f.z;
            tile[kr][cg * 16 + q * 4 + 3] = f.w;
        }
    }
    __syncthreads();
    {
        int nr = tid >> 2, kg = tid & 3;
        int n = n0 + nr;
        bf16x8 h0, h1, lo0, lo1;
        #pragma unroll
        for (int e = 0; e < 8; ++e) {
            float a = tile[kg * 16 + e][nr];
            float b = tile[kg * 16 + 8 + e][nr];
            unsigned short ha = f2bf(a), hb = f2bf(b);
            h0[e] = (short)ha; h1[e] = (short)hb;
            lo0[e] = (short)f2bf(a - bf2f(ha));
            lo1[e] = (short)f2bf(b - bf2f(hb));
        }
        short* dh = hi + (size_t)n * 1024 + k0 + kg * 16;
        *(bf16x8*)dh = h0;
        *(bf16x8*)(dh + 8) = h1;
        if (lo) {
            short* dl = lo + (size_t)n * 1024 + k0 + kg * 16;
            *(bf16x8*)dl = lo0;
            *(bf16x8*)(dl + 8) = lo1;
        }
    }
}

// ---------------------------------------------------------------------------
// Repack V: v bf16 [B*T][C] -> Vt bf16 [B][H][64][T]
// ---------------------------------------------------------------------------
__global__ __launch_bounds__(256) void repack_vt_kernel(
    const short* __restrict__ v, short* __restrict__ vt)
{
    __shared__ short tile[64][80];
    const int tid = threadIdx.x;
    const int tt = blockIdx.x, h = blockIdx.y, b = blockIdx.z;
    const int t0 = tt * 64;
    {
        int tr = tid >> 2, cgrp = tid & 3;
        const short* src = v + (size_t)(b * T_SEQ + t0 + tr) * CEMB + h * DHEAD + cgrp * 16;
        *(bf16x8*)&tile[tr][cgrp * 16]     = *(const bf16x8*)src;
        *(bf16x8*)&tile[tr][cgrp * 16 + 8] = *(const bf16x8*)(src + 8);
    }
    __syncthreads();
    {
        int d = tid >> 2, tc = tid & 3;
        short s[16];
        #pragma unroll
        for (int e = 0; e < 16; ++e) s[e] = tile[tc * 16 + e][d];
        short* dst = vt + ((size_t)((b * NHEAD + h) * DHEAD + d)) * T_SEQ + t0 + tc * 16;
        bf16x8 v0, v1;
        #pragma unroll
        for (int e = 0; e < 8; ++e) { v0[e] = s[e]; v1[e] = s[8 + e]; }
        *(bf16x8*)dst       = v0;
        *(bf16x8*)(dst + 8) = v1;
    }
}

// ---------------------------------------------------------------------------
// MFMA flash attention (causal). Inputs pre-split bf16:
//  - qkhi/qklo [B*T][2048]: q cols 0..1023 (pre-scaled by 32*log2e), k cols 1024..2047
//  - Vt bf16 [B][H][64][T]; output ctx bf16 [B*T][1024]
// All K/V staging via global_load_lds with pre-swizzled source addresses.
// Double-buffered K/V LDS + one-step prefetch. Softmax in exp2 domain with
// exact defer-rescale (skip alpha pass when tile max <= running max).
// ---------------------------------------------------------------------------
__global__ __launch_bounds__(256) void attn_mfma_kernel(
    const short* __restrict__ qkhi, const short* __restrict__ qklo,
    const short* __restrict__ vt, short* __restrict__ ctxb)
{
    // shorts: Khi[2][4096] @0, Klo[2][4096] @8192, Vs[2][4096] @16384, Ps @24576
    __shared__ __align__(16) short smem[32768];

    const int tid = threadIdx.x;
    const int w = tid >> 6, l = tid & 63;
    const int lr = l & 15, lg = l >> 4;

    const int bid = blockIdx.x;
    const int pr = bid & 7, bh = bid >> 3;
    const int h = bh & 15, b = bh >> 4;
    const size_t bT = (size_t)b * T_SEQ;

    // staging granule geometry: issues i=0,1 -> granule g = w*128 + i*64 + l
    const int g0 = w * 128 + l, g1 = g0 + 64;
    const int rg[2] = {g0 >> 3, g1 >> 3};
    const int sc[2] = {(g0 & 7) ^ (rg[0] & 7), (g1 & 7) ^ (rg[1] & 7)};
    short* const dst0 = &smem[(w * 128) * 8];
    short* const dst1 = &smem[(w * 128 + 64) * 8];

    for (int half = 0; half < 2; ++half) {
        const int xi = half ? (15 - pr) : pr;
        const int q0 = xi * 128;
        const int qw = q0 + w * 32;

        // Q fragments: direct bf16 loads (pre-scaled, pre-split)
        bf16x8 ahi[2][2], alo[2][2];
        #pragma unroll
        for (int rt = 0; rt < 2; ++rt) {
            #pragma unroll
            for (int kk = 0; kk < 2; ++kk) {
                size_t off = (bT + qw + rt * 16 + lr) * 2048 + h * DHEAD + kk * 32 + lg * 8;
                ahi[rt][kk] = *(const bf16x8*)(qkhi + off);
                alo[rt][kk] = *(const bf16x8*)(qklo + off);
            }
        }

        f32x4 O[2][4];
        #pragma unroll
        for (int rt = 0; rt < 2; ++rt)
            #pragma unroll
            for (int dt = 0; dt < 4; ++dt)
                O[rt][dt] = (f32x4){0.f, 0.f, 0.f, 0.f};
        float mrun[2][4], lrun[2][4];
        #pragma unroll
        for (int rt = 0; rt < 2; ++rt)
            #pragma unroll
            for (int r = 0; r < 4; ++r) { mrun[rt][r] = -3.0e38f; lrun[rt][r] = 0.f; }

        // staging pointers (j0 = 0)
        const short* pKh[2]; const short* pKl[2]; const short* pV[2];
        #pragma unroll
        for (int i = 0; i < 2; ++i) {
            size_t koff = (bT + rg[i]) * 2048 + 1024 + h * DHEAD + sc[i] * 8;
            pKh[i] = qkhi + koff;
            pKl[i] = qklo + koff;
            pV[i]  = vt + ((size_t)((b * NHEAD + h) * DHEAD) + rg[i]) * T_SEQ + sc[i] * 8;
        }

        #define STAGE(buf)  do {                                                  \
            gload16(pKh[0], dst0 + (buf) * 4096);                                 \
            gload16(pKh[1], dst1 + (buf) * 4096);                                 \
            gload16(pKl[0], dst0 + 8192 + (buf) * 4096);                          \
            gload16(pKl[1], dst1 + 8192 + (buf) * 4096);                          \
            gload16(pV[0],  dst0 + 16384 + (buf) * 4096);                         \
            gload16(pV[1],  dst1 + 16384 + (buf) * 4096);                         \
            pKh[0] += 64 * 2048; pKh[1] += 64 * 2048;                             \
            pKl[0] += 64 * 2048; pKl[1] += 64 * 2048;                             \
            pV[0]  += 64;        pV[1]  += 64;                                    \
        } while (0)

        const int nsteps = 2 * xi + 2;   // always even
        STAGE(0);
        for (int t = 0; t < nsteps; ++t) {
            const int j0 = t * 64;
            __syncthreads();                 // drains vmcnt -> tile t ready
            if (t + 1 < nsteps) STAGE((t + 1) & 1);
            const int kb = (t & 1) * 4096;

            #pragma unroll
            for (int rt = 0; rt < 2; ++rt) {
                if (j0 > qw + rt * 16 + 15) continue;   // fully masked rt-tile

                f32x4 S[4];
                #pragma unroll
                for (int ct = 0; ct < 4; ++ct) {
                    f32x4 s = (f32x4){0.f, 0.f, 0.f, 0.f};
                    #pragma unroll
                    for (int kk = 0; kk < 2; ++kk) {
                        int j  = ct * 16 + lr;
                        int ck = kk * 4 + lg;
                        int idx = kb + j * 64 + ((ck ^ (j & 7)) << 3);
                        bf16x8 bh8 = *(bf16x8*)&smem[idx];
                        bf16x8 bl8 = *(bf16x8*)&smem[8192 + idx];
                        s = __builtin_amdgcn_mfma_f32_16x16x32_bf16(ahi[rt][kk], bh8, s, 0, 0, 0);
                        s = __builtin_amdgcn_mfma_f32_16x16x32_bf16(alo[rt][kk], bh8, s, 0, 0, 0);
                        s = __builtin_amdgcn_mfma_f32_16x16x32_bf16(ahi[rt][kk], bl8, s, 0, 0, 0);
                    }
                    if (j0 + ct * 16 + 15 > qw + rt * 16) {
                        int jabs = j0 + ct * 16 + lr;
                        #pragma unroll
                        for (int r = 0; r < 4; ++r) {
                            int qabs = qw + rt * 16 + lg * 4 + r;
                            s[r] = (jabs <= qabs) ? s[r] : -3.0e38f;
                        }
                    }
                    S[ct] = s;
                }

                // tile max per row
                float tm[4];
                #pragma unroll
                for (int r = 0; r < 4; ++r) {
                    float v = fmaxf(fmaxf(S[0][r], S[1][r]), fmaxf(S[2][r], S[3][r]));
                    v = fmaxf(v, __shfl_xor(v, 1));
                    v = fmaxf(v, __shfl_xor(v, 2));
                    v = fmaxf(v, __shfl_xor(v, 4));
                    v = fmaxf(v, __shfl_xor(v, 8));
                    tm[r] = v;
                }
                bool exceed = (tm[0] > mrun[rt][0]) | (tm[1] > mrun[rt][1]) |
                              (tm[2] > mrun[rt][2]) | (tm[3] > mrun[rt][3]);
                if (__any(exceed)) {   // rescale pass (exact skip otherwise)
                    #pragma unroll
                    for (int r = 0; r < 4; ++r) {
                        float mnew  = fmaxf(mrun[rt][r], tm[r]);
                        float alpha = __builtin_amdgcn_exp2f(mrun[rt][r] - mnew);
                        mrun[rt][r] = mnew;
                        lrun[rt][r] *= alpha;
                        #pragma unroll
                        for (int dt = 0; dt < 4; ++dt)
                            O[rt][dt][r] *= alpha;
                    }
                }

                float lsum[4] = {0.f, 0.f, 0.f, 0.f};
                #pragma unroll
                for (int ct = 0; ct < 4; ++ct) {
                    #pragma unroll
                    for (int r = 0; r < 4; ++r) {
                        float p = __builtin_amdgcn_exp2f(S[ct][r] - mrun[rt][r]);
                        lsum[r] += p;
                        int row = rt * 16 + lg * 4 + r;
                        int col = ct * 16 + lr;
                        smem[24576 + w * 2048 + row * 64 + (col ^ ((row & 7) << 3))] = (short)f2bf(p);
                    }
                }
                #pragma unroll
                for (int r = 0; r < 4; ++r) {
                    float s = lsum[r];
                    s += __shfl_xor(s, 1);
                    s += __shfl_xor(s, 2);
                    s += __shfl_xor(s, 4);
                    s += __shfl_xor(s, 8);
                    lrun[rt][r] += s;
                }
            }

            __builtin_amdgcn_wave_barrier();  // order P writes before P reads

            #pragma unroll
            for (int rt = 0; rt < 2; ++rt) {
                if (j0 > qw + rt * 16 + 15) continue;
                bf16x8 pa[2];
                #pragma unroll
                for (int jk = 0; jk < 2; ++jk) {
                    int row = rt * 16 + lr;
                    int ck  = jk * 4 + lg;
                    pa[jk] = *(bf16x8*)&smem[24576 + w * 2048 + row * 64 + ((ck ^ (row & 7)) << 3)];
                }
                #pragma unroll
                for (int dt = 0; dt < 4; ++dt) {
                    #pragma unroll
                    for (int jk = 0; jk < 2; ++jk) {
                        int d   = dt * 16 + lr;
                        int ck  = jk * 4 + lg;
                        bf16x8 vb = *(bf16x8*)&smem[16384 + kb + d * 64 + ((ck ^ (d & 7)) << 3)];
                        O[rt][dt] = __builtin_amdgcn_mfma_f32_16x16x32_bf16(pa[jk], vb, O[rt][dt], 0, 0, 0);
                    }
                }
            }
        }
        #undef STAGE

        #pragma unroll
        for (int rt = 0; rt < 2; ++rt) {
            #pragma unroll
            for (int r = 0; r < 4; ++r) {
                float inv = 1.0f / lrun[rt][r];
                int row = qw + rt * 16 + lg * 4 + r;
                #pragma unroll
                for (int dt = 0; dt < 4; ++dt) {
                    int col = h * DHEAD + dt * 16 + lr;
                    ctxb[(size_t)(b * T_SEQ + row) * CEMB + col] = (short)f2bf(O[rt][dt][r] * inv);
                }
            }
        }
    }
}

// ---------------------------------------------------------------------------
extern "C" void kernel_launch(void* const* d_in, const int* in_sizes, int n_in,
                              void* d_out, int out_size, void* d_ws, size_t ws_size,
                              hipStream_t stream)
{
    const float* x    = (const float*)d_in[0];
    const float* Wqkv = (const float*)d_in[1];
    const float* bqkv = (const float*)d_in[2];
    const float* Wo   = (const float*)d_in[3];
    const float* bo   = (const float*)d_in[4];
    float* out = (float*)d_out;

    // Workspace (110 MB):
    char* ws = (char*)d_ws;
    short* qkhi = (short*)ws;                           // 32 MB [8192][2048] (late)
    short* vbuf = (short*)ws;                           // 16 MB [8192][1024] (early, dead before qk)
    short* qklo = (short*)(ws + (size_t)(32u << 20));   // 32 MB
    short* Vt   = (short*)(ws + (size_t)(64u << 20));   // 16 MB [B][H][64][T]
    short* ctxb = (short*)(ws + (size_t)(80u << 20));   // 16 MB [8192][1024]
    short* WhiT = (short*)(ws + (size_t)(96u << 20));   // 6 MB [3072][1024]
    short* WloT = (short*)(ws + (size_t)(102u << 20));  // 6 MB
    short* WoT  = (short*)(ws + (size_t)(108u << 20));  // 2 MB [1024][1024]

    const int M = 4 * T_SEQ;  // 8192

    // 1) weight transpose+split
    transpose_split_kernel<<<dim3(48, 16), 256, 0, stream>>>(Wqkv, 3 * CEMB, WhiT, WloT);
    transpose_split_kernel<<<dim3(16, 16), 256, 0, stream>>>(Wo, CEMB, WoT, nullptr);

    // 2) V = x @ Wv + bv  (bf16 out)
    gemm_mfma_kernel<1, true, 1><<<dim3(8, 64), 256, 0, stream>>>(
        x, nullptr, WhiT + (size_t)2048 * 1024, nullptr, bqkv + 2048, vbuf, nullptr, CEMB, CEMB);

    // 3) repack V -> Vt
    repack_vt_kernel<<<dim3(32, 16, 4), 256, 0, stream>>>(vbuf, Vt);

    // 4) qk = x @ Wqk + b  -> split hi/lo bf16, q cols pre-scaled (overwrites vbuf)
    gemm_mfma_kernel<3, true, 2><<<dim3(16, 64), 256, 0, stream>>>(
        x, nullptr, WhiT, WloT, bqkv, qkhi, qklo, CEMB, 2048);

    // 5) causal MFMA flash attention -> ctx bf16
    attn_mfma_kernel<<<dim3(512), 256, 0, stream>>>(qkhi, qklo, Vt, ctxb);

    // 6) out = ctx @ Wo + bo  (fp32 out)
    gemm_mfma_kernel<1, false, 0><<<dim3(8, 64), 256, 0, stream>>>(
        nullptr, ctxb, WoT, nullptr, bo, out, nullptr, CEMB, CEMB);
}

// Round 6
// 385.955 us; speedup vs baseline: 1.2397x; 1.2397x over previous
//
#include <hip/hip_runtime.h>
#include <cstdint>
#include <cstddef>

// Problem constants: B=4, T=2048, C=1024, H=16, d=64
#define T_SEQ 2048
#define CEMB  1024
#define NHEAD 16
#define DHEAD 64

// q pre-scale: 32 (sqrt(C) quirk) * log2(e)  -> logits in log2 units
#define QSCALE 46.1662413084468f

typedef __attribute__((ext_vector_type(8))) short bf16x8;
typedef __attribute__((ext_vector_type(4))) float f32x4;

static __device__ __forceinline__ unsigned short f2bf(float x) {
    unsigned u = __builtin_bit_cast(unsigned, x);
    unsigned r = (u + 0x7FFFu + ((u >> 16) & 1u)) >> 16;
    return (unsigned short)r;
}
static __device__ __forceinline__ float bf2f(unsigned short b) {
    unsigned u = ((unsigned)b) << 16;
    return __builtin_bit_cast(float, u);
}

// async global->LDS: 16B per lane; ldsbase wave-uniform, lane offset = lane*16B.
static __device__ __forceinline__ void gload16(const short* gsrc, short* ldsbase) {
    __builtin_amdgcn_global_load_lds(
        (const __attribute__((address_space(1))) void*)gsrc,
        (__attribute__((address_space(3))) void*)ldsbase, 16, 0, 0);
}

// ---------------------------------------------------------------------------
// MFMA GEMM, 128x128 tile, BK=32, 256 threads (4 waves, 2x2).
//   C[M][N] = A[M][K] @ B^T[N][K]^T + bias[N]
// SPLIT==3: A,B split hi/lo bf16, 3 MFMAs (hh+lh+hl) -> ~fp32 product.
// A_F32: A read fp32, split in staging. Else A bf16 via global_load_lds.
// OUT_MODE: 0 = fp32, 1 = bf16, 2 = split hi/lo bf16 (cols<1024 scaled QSCALE).
// ---------------------------------------------------------------------------
template<int SPLIT, bool A_F32, int OUT_MODE>
__global__ __launch_bounds__(256) void gemm_mfma_kernel(
    const float* __restrict__ Af, const short* __restrict__ Ah,
    const short* __restrict__ Bh, const short* __restrict__ Bl,
    const float* __restrict__ bias,
    void* __restrict__ Cout, void* __restrict__ Cout2, int K, int ldc)
{
    __shared__ __align__(16) short smem[(SPLIT == 3) ? 16384 : 8192];

    const int tid = threadIdx.x;
    const int w = tid >> 6, l = tid & 63;
    const int lr = l & 15, lg = l >> 4;
    const int wr = w >> 1, wc = w & 1;
    const int row0 = blockIdx.y * 128;
    const int col0 = blockIdx.x * 128;

    f32x4 acc[4][4];
    #pragma unroll
    for (int mt = 0; mt < 4; ++mt)
        #pragma unroll
        for (int nt = 0; nt < 4; ++nt)
            acc[mt][nt] = (f32x4){0.f, 0.f, 0.f, 0.f};

    const int sB0 = w * 128 + l, sB1 = sB0 + 64;
    const short* gB0 = Bh + (size_t)(col0 + (sB0 & 127)) * K + (sB0 >> 7) * 8;
    const short* gB1 = Bh + (size_t)(col0 + (sB1 & 127)) * K + (sB1 >> 7) * 8;
    short* dB0 = &smem[4096 + (w * 128) * 8];
    short* dB1 = &smem[4096 + (w * 128 + 64) * 8];
    const short* gBl0 = nullptr; const short* gBl1 = nullptr;
    if constexpr (SPLIT == 3) {
        gBl0 = Bl + (size_t)(col0 + (sB0 & 127)) * K + (sB0 >> 7) * 8;
        gBl1 = Bl + (size_t)(col0 + (sB1 & 127)) * K + (sB1 >> 7) * 8;
    }
    const short* gA0 = nullptr; const short* gA1 = nullptr;
    if constexpr (!A_F32) {
        gA0 = Ah + (size_t)(row0 + (sB0 & 127)) * K + (sB0 >> 7) * 8;
        gA1 = Ah + (size_t)(row0 + (sB1 & 127)) * K + (sB1 >> 7) * 8;
    }
    short* dA0 = &smem[(w * 128) * 8];
    short* dA1 = &smem[(w * 128 + 64) * 8];

    const int arow = tid >> 1, ahalf = tid & 1;
    const float* gAf = A_F32 ? (Af + (size_t)(row0 + arow) * K + ahalf * 16) : nullptr;

    for (int kt = 0; kt < K; kt += 32) {
        __syncthreads();
        if constexpr (!A_F32) {
            gload16(gA0 + kt, dA0);
            gload16(gA1 + kt, dA1);
        }
        gload16(gB0 + kt, dB0);
        gload16(gB1 + kt, dB1);
        if constexpr (SPLIT == 3) {
            gload16(gBl0 + kt, &smem[12288 + (w * 128) * 8]);
            gload16(gBl1 + kt, &smem[12288 + (w * 128 + 64) * 8]);
        }
        if constexpr (A_F32) {
            const float* src = gAf + kt;
            float4 f0 = *(const float4*)(src);
            float4 f1 = *(const float4*)(src + 4);
            float4 f2 = *(const float4*)(src + 8);
            float4 f3 = *(const float4*)(src + 12);
            float xs[16] = {f0.x, f0.y, f0.z, f0.w, f1.x, f1.y, f1.z, f1.w,
                            f2.x, f2.y, f2.z, f2.w, f3.x, f3.y, f3.z, f3.w};
            #pragma unroll
            for (int q = 0; q < 2; ++q) {
                bf16x8 h8, l8;
                #pragma unroll
                for (int e = 0; e < 8; ++e) {
                    float x = xs[q * 8 + e];
                    if constexpr (SPLIT == 3) {
                        unsigned u = __builtin_bit_cast(unsigned, x);
                        h8[e] = (short)(unsigned short)(u >> 16);
                        float hf = __builtin_bit_cast(float, u & 0xFFFF0000u);
                        l8[e] = (short)f2bf(x - hf);
                    } else {
                        h8[e] = (short)f2bf(x);
                    }
                }
                int slot = (ahalf * 2 + q) * 128 + arow;
                *(bf16x8*)&smem[slot * 8] = h8;
                if constexpr (SPLIT == 3) *(bf16x8*)&smem[8192 + slot * 8] = l8;
            }
        }
        __syncthreads();

        const int aoff = (lg * 128 + wr * 64 + lr) * 8;
        const int boff = 4096 + (lg * 128 + wc * 64 + lr) * 8;
        bf16x8 ahf[4], alf[4];
        #pragma unroll
        for (int mt = 0; mt < 4; ++mt) {
            ahf[mt] = *(const bf16x8*)&smem[aoff + mt * 128];
            if constexpr (SPLIT == 3)
                alf[mt] = *(const bf16x8*)&smem[8192 + aoff + mt * 128];
        }
        #pragma unroll
        for (int nt = 0; nt < 4; ++nt) {
            bf16x8 bhf = *(const bf16x8*)&smem[boff + nt * 128];
            if constexpr (SPLIT == 3) {
                bf16x8 blf = *(const bf16x8*)&smem[8192 + boff + nt * 128];
                #pragma unroll
                for (int mt = 0; mt < 4; ++mt) {
                    acc[mt][nt] = __builtin_amdgcn_mfma_f32_16x16x32_bf16(ahf[mt], bhf, acc[mt][nt], 0, 0, 0);
                    acc[mt][nt] = __builtin_amdgcn_mfma_f32_16x16x32_bf16(alf[mt], bhf, acc[mt][nt], 0, 0, 0);
                    acc[mt][nt] = __builtin_amdgcn_mfma_f32_16x16x32_bf16(ahf[mt], blf, acc[mt][nt], 0, 0, 0);
                }
            } else {
                #pragma unroll
                for (int mt = 0; mt < 4; ++mt)
                    acc[mt][nt] = __builtin_amdgcn_mfma_f32_16x16x32_bf16(ahf[mt], bhf, acc[mt][nt], 0, 0, 0);
            }
        }
    }

    #pragma unroll
    for (int mt = 0; mt < 4; ++mt) {
        #pragma unroll
        for (int r = 0; r < 4; ++r) {
            int m = row0 + wr * 64 + mt * 16 + lg * 4 + r;
            #pragma unroll
            for (int nt = 0; nt < 4; ++nt) {
                int n = col0 + wc * 64 + nt * 16 + lr;
                float v = acc[mt][nt][r] + bias[n];
                if constexpr (OUT_MODE == 0) {
                    ((float*)Cout)[(size_t)m * ldc + n] = v;
                } else if constexpr (OUT_MODE == 1) {
                    ((short*)Cout)[(size_t)m * ldc + n] = (short)f2bf(v);
                } else {
                    if (n < 1024) v *= QSCALE;
                    unsigned u = __builtin_bit_cast(unsigned, v);
                    ((short*)Cout)[(size_t)m * ldc + n] = (short)(unsigned short)(u >> 16);
                    float hf = __builtin_bit_cast(float, u & 0xFFFF0000u);
                    ((short*)Cout2)[(size_t)m * ldc + n] = (short)f2bf(v - hf);
                }
            }
        }
    }
}

// ---------------------------------------------------------------------------
// Transpose + hi/lo bf16 split: src fp32 [Krows][nsrc] -> hi/lo [N][1024]
// ---------------------------------------------------------------------------
__global__ __launch_bounds__(256) void transpose_split_kernel(
    const float* __restrict__ src, int nsrc,
    short* __restrict__ hi, short* __restrict__ lo)
{
    __shared__ float tile[64][68];
    const int tid = threadIdx.x;
    const int n0 = blockIdx.x * 64, k0 = blockIdx.y * 64;
    {
        int kr = tid >> 2, cg = tid & 3;
        const float* s = src + (size_t)(k0 + kr) * nsrc + n0 + cg * 16;
        #pragma unroll
        for (int q = 0; q < 4; ++q) {
            float4 f = *(const float4*)(s + q * 4);
            tile[kr][cg * 16 + q * 4 + 0] = f.x;
            tile[kr][cg * 16 + q * 4 + 1] = f.y;
            tile[kr][cg * 16 + q * 4 + 2] = f.z;
            tile[kr][cg * 16 + q * 4 + 3] = f.w;
        }
    }
    __syncthreads();
    {
        int nr = tid >> 2, kg = tid & 3;
        int n = n0 + nr;
        bf16x8 h0, h1, lo0, lo1;
        #pragma unroll
        for (int e = 0; e < 8; ++e) {
            float a = tile[kg * 16 + e][nr];
            float b = tile[kg * 16 + 8 + e][nr];
            unsigned short ha = f2bf(a), hb = f2bf(b);
            h0[e] = (short)ha; h1[e] = (short)hb;
            lo0[e] = (short)f2bf(a - bf2f(ha));
            lo1[e] = (short)f2bf(b - bf2f(hb));
        }
        short* dh = hi + (size_t)n * 1024 + k0 + kg * 16;
        *(bf16x8*)dh = h0;
        *(bf16x8*)(dh + 8) = h1;
        if (lo) {
            short* dl = lo + (size_t)n * 1024 + k0 + kg * 16;
            *(bf16x8*)dl = lo0;
            *(bf16x8*)(dl + 8) = lo1;
        }
    }
}

// ---------------------------------------------------------------------------
// Repack V: v bf16 [B*T][C] -> Vt bf16 [B][H][64][T]
// ---------------------------------------------------------------------------
__global__ __launch_bounds__(256) void repack_vt_kernel(
    const short* __restrict__ v, short* __restrict__ vt)
{
    __shared__ short tile[64][80];
    const int tid = threadIdx.x;
    const int tt = blockIdx.x, h = blockIdx.y, b = blockIdx.z;
    const int t0 = tt * 64;
    {
        int tr = tid >> 2, cgrp = tid & 3;
        const short* src = v + (size_t)(b * T_SEQ + t0 + tr) * CEMB + h * DHEAD + cgrp * 16;
        *(bf16x8*)&tile[tr][cgrp * 16]     = *(const bf16x8*)src;
        *(bf16x8*)&tile[tr][cgrp * 16 + 8] = *(const bf16x8*)(src + 8);
    }
    __syncthreads();
    {
        int d = tid >> 2, tc = tid & 3;
        short s[16];
        #pragma unroll
        for (int e = 0; e < 16; ++e) s[e] = tile[tc * 16 + e][d];
        short* dst = vt + ((size_t)((b * NHEAD + h) * DHEAD + d)) * T_SEQ + t0 + tc * 16;
        bf16x8 v0, v1;
        #pragma unroll
        for (int e = 0; e < 8; ++e) { v0[e] = s[e]; v1[e] = s[8 + e]; }
        *(bf16x8*)dst       = v0;
        *(bf16x8*)(dst + 8) = v1;
    }
}

// ---------------------------------------------------------------------------
// MFMA flash attention (causal). Inputs pre-split bf16:
//  - qkhi/qklo [B*T][2048]: q cols 0..1023 (pre-scaled by 32*log2e), k cols 1024..2047
//  - Vt bf16 [B][H][64][T]; output ctx bf16 [B*T][1024]
// Single-buffered K/V LDS (40 KB total -> 4 blocks/CU), staging via
// global_load_lds with pre-swizzled source addresses (zero staging VALU).
// Softmax in exp2 domain with exact defer-rescale.
// ---------------------------------------------------------------------------
__global__ __launch_bounds__(256) void attn_mfma_kernel(
    const short* __restrict__ qkhi, const short* __restrict__ qklo,
    const short* __restrict__ vt, short* __restrict__ ctxb)
{
    // shorts: Khi @0 (4096), Klo @4096, Vs @8192, Ps @12288 (8192) = 40960 B
    __shared__ __align__(16) short smem[20480];

    const int tid = threadIdx.x;
    const int w = tid >> 6, l = tid & 63;
    const int lr = l & 15, lg = l >> 4;

    const int bid = blockIdx.x;
    const int pr = bid & 7, bh = bid >> 3;
    const int h = bh & 15, b = bh >> 4;
    const size_t bT = (size_t)b * T_SEQ;

    // staging granule geometry: issues i=0,1 -> granule g = w*128 + i*64 + l
    const int g0 = w * 128 + l, g1 = g0 + 64;
    const int rg0 = g0 >> 3, rg1 = g1 >> 3;                    // LDS row 0..63
    const int sc0 = (g0 & 7) ^ (rg0 & 7), sc1 = (g1 & 7) ^ (rg1 & 7);  // swizzled chunk
    short* const dst0 = &smem[(w * 128) * 8];
    short* const dst1 = &smem[(w * 128 + 64) * 8];

    // global source bases (row rg, swizzle-chunk sc pre-applied)
    const size_t koff0 = (bT + rg0) * 2048 + 1024 + h * DHEAD + sc0 * 8;
    const size_t koff1 = (bT + rg1) * 2048 + 1024 + h * DHEAD + sc1 * 8;
    const short* const pKh0 = qkhi + koff0;
    const short* const pKh1 = qkhi + koff1;
    const short* const pKl0 = qklo + koff0;
    const short* const pKl1 = qklo + koff1;
    const short* const pV0 = vt + ((size_t)((b * NHEAD + h) * DHEAD) + rg0) * T_SEQ + sc0 * 8;
    const short* const pV1 = vt + ((size_t)((b * NHEAD + h) * DHEAD) + rg1) * T_SEQ + sc1 * 8;

    for (int half = 0; half < 2; ++half) {
        const int xi = half ? (15 - pr) : pr;
        const int q0 = xi * 128;
        const int qw = q0 + w * 32;

        // Q fragments: direct bf16 loads (pre-scaled, pre-split)
        bf16x8 ahi[2][2], alo[2][2];
        #pragma unroll
        for (int rt = 0; rt < 2; ++rt) {
            #pragma unroll
            for (int kk = 0; kk < 2; ++kk) {
                size_t off = (bT + qw + rt * 16 + lr) * 2048 + h * DHEAD + kk * 32 + lg * 8;
                ahi[rt][kk] = *(const bf16x8*)(qkhi + off);
                alo[rt][kk] = *(const bf16x8*)(qklo + off);
            }
        }

        f32x4 O[2][4];
        #pragma unroll
        for (int rt = 0; rt < 2; ++rt)
            #pragma unroll
            for (int dt = 0; dt < 4; ++dt)
                O[rt][dt] = (f32x4){0.f, 0.f, 0.f, 0.f};
        float mrun[2][4], lrun[2][4];
        #pragma unroll
        for (int rt = 0; rt < 2; ++rt)
            #pragma unroll
            for (int r = 0; r < 4; ++r) { mrun[rt][r] = -3.0e38f; lrun[rt][r] = 0.f; }

        const int nsteps = 2 * xi + 2;
        for (int t = 0; t < nsteps; ++t) {
            const int j0 = t * 64;
            __syncthreads();                 // prior-step readers done
            // stage K hi/lo + V for rows j0..j0+63 (pure DMA, no VALU)
            gload16(pKh0 + (size_t)j0 * 2048, dst0);
            gload16(pKh1 + (size_t)j0 * 2048, dst1);
            gload16(pKl0 + (size_t)j0 * 2048, dst0 + 4096);
            gload16(pKl1 + (size_t)j0 * 2048, dst1 + 4096);
            gload16(pV0 + j0, dst0 + 8192);
            gload16(pV1 + j0, dst1 + 8192);
            __syncthreads();                 // drains vmcnt -> tile ready

            #pragma unroll
            for (int rt = 0; rt < 2; ++rt) {
                if (j0 > qw + rt * 16 + 15) continue;   // fully masked rt-tile

                f32x4 S[4];
                #pragma unroll
                for (int ct = 0; ct < 4; ++ct) {
                    f32x4 s = (f32x4){0.f, 0.f, 0.f, 0.f};
                    #pragma unroll
                    for (int kk = 0; kk < 2; ++kk) {
                        int j  = ct * 16 + lr;
                        int ck = kk * 4 + lg;
                        int idx = j * 64 + ((ck ^ (j & 7)) << 3);
                        bf16x8 bh8 = *(bf16x8*)&smem[idx];
                        bf16x8 bl8 = *(bf16x8*)&smem[4096 + idx];
                        s = __builtin_amdgcn_mfma_f32_16x16x32_bf16(ahi[rt][kk], bh8, s, 0, 0, 0);
                        s = __builtin_amdgcn_mfma_f32_16x16x32_bf16(alo[rt][kk], bh8, s, 0, 0, 0);
                        s = __builtin_amdgcn_mfma_f32_16x16x32_bf16(ahi[rt][kk], bl8, s, 0, 0, 0);
                    }
                    if (j0 + ct * 16 + 15 > qw + rt * 16) {
                        int jabs = j0 + ct * 16 + lr;
                        #pragma unroll
                        for (int r = 0; r < 4; ++r) {
                            int qabs = qw + rt * 16 + lg * 4 + r;
                            s[r] = (jabs <= qabs) ? s[r] : -3.0e38f;
                        }
                    }
                    S[ct] = s;
                }

                float tm[4];
                #pragma unroll
                for (int r = 0; r < 4; ++r) {
                    float v = fmaxf(fmaxf(S[0][r], S[1][r]), fmaxf(S[2][r], S[3][r]));
                    v = fmaxf(v, __shfl_xor(v, 1));
                    v = fmaxf(v, __shfl_xor(v, 2));
                    v = fmaxf(v, __shfl_xor(v, 4));
                    v = fmaxf(v, __shfl_xor(v, 8));
                    tm[r] = v;
                }
                bool exceed = (tm[0] > mrun[rt][0]) | (tm[1] > mrun[rt][1]) |
                              (tm[2] > mrun[rt][2]) | (tm[3] > mrun[rt][3]);
                if (__any(exceed)) {   // rescale pass (exact skip otherwise)
                    #pragma unroll
                    for (int r = 0; r < 4; ++r) {
                        float mnew  = fmaxf(mrun[rt][r], tm[r]);
                        float alpha = __builtin_amdgcn_exp2f(mrun[rt][r] - mnew);
                        mrun[rt][r] = mnew;
                        lrun[rt][r] *= alpha;
                        #pragma unroll
                        for (int dt = 0; dt < 4; ++dt)
                            O[rt][dt][r] *= alpha;
                    }
                }

                float lsum[4] = {0.f, 0.f, 0.f, 0.f};
                #pragma unroll
                for (int ct = 0; ct < 4; ++ct) {
                    #pragma unroll
                    for (int r = 0; r < 4; ++r) {
                        float p = __builtin_amdgcn_exp2f(S[ct][r] - mrun[rt][r]);
                        lsum[r] += p;
                        int row = rt * 16 + lg * 4 + r;
                        int col = ct * 16 + lr;
                        smem[12288 + w * 2048 + row * 64 + (col ^ ((row & 7) << 3))] = (short)f2bf(p);
                    }
                }
                #pragma unroll
                for (int r = 0; r < 4; ++r) {
                    float s = lsum[r];
                    s += __shfl_xor(s, 1);
                    s += __shfl_xor(s, 2);
                    s += __shfl_xor(s, 4);
                    s += __shfl_xor(s, 8);
                    lrun[rt][r] += s;
                }
            }

            __builtin_amdgcn_wave_barrier();  // order P writes before P reads

            #pragma unroll
            for (int rt = 0; rt < 2; ++rt) {
                if (j0 > qw + rt * 16 + 15) continue;
                bf16x8 pa[2];
                #pragma unroll
                for (int jk = 0; jk < 2; ++jk) {
                    int row = rt * 16 + lr;
                    int ck  = jk * 4 + lg;
                    pa[jk] = *(bf16x8*)&smem[12288 + w * 2048 + row * 64 + ((ck ^ (row & 7)) << 3)];
                }
                #pragma unroll
                for (int dt = 0; dt < 4; ++dt) {
                    #pragma unroll
                    for (int jk = 0; jk < 2; ++jk) {
                        int d   = dt * 16 + lr;
                        int ck  = jk * 4 + lg;
                        bf16x8 vb = *(bf16x8*)&smem[8192 + d * 64 + ((ck ^ (d & 7)) << 3)];
                        O[rt][dt] = __builtin_amdgcn_mfma_f32_16x16x32_bf16(pa[jk], vb, O[rt][dt], 0, 0, 0);
                    }
                }
            }
        }

        #pragma unroll
        for (int rt = 0; rt < 2; ++rt) {
            #pragma unroll
            for (int r = 0; r < 4; ++r) {
                float inv = 1.0f / lrun[rt][r];
                int row = qw + rt * 16 + lg * 4 + r;
                #pragma unroll
                for (int dt = 0; dt < 4; ++dt) {
                    int col = h * DHEAD + dt * 16 + lr;
                    ctxb[(size_t)(b * T_SEQ + row) * CEMB + col] = (short)f2bf(O[rt][dt][r] * inv);
                }
            }
        }
    }
}

// ---------------------------------------------------------------------------
extern "C" void kernel_launch(void* const* d_in, const int* in_sizes, int n_in,
                              void* d_out, int out_size, void* d_ws, size_t ws_size,
                              hipStream_t stream)
{
    const float* x    = (const float*)d_in[0];
    const float* Wqkv = (const float*)d_in[1];
    const float* bqkv = (const float*)d_in[2];
    const float* Wo   = (const float*)d_in[3];
    const float* bo   = (const float*)d_in[4];
    float* out = (float*)d_out;

    // Workspace (110 MB):
    char* ws = (char*)d_ws;
    short* qkhi = (short*)ws;                           // 32 MB [8192][2048] (late)
    short* vbuf = (short*)ws;                           // 16 MB [8192][1024] (early, dead before qk)
    short* qklo = (short*)(ws + (size_t)(32u << 20));   // 32 MB
    short* Vt   = (short*)(ws + (size_t)(64u << 20));   // 16 MB [B][H][64][T]
    short* ctxb = (short*)(ws + (size_t)(80u << 20));   // 16 MB [8192][1024]
    short* WhiT = (short*)(ws + (size_t)(96u << 20));   // 6 MB [3072][1024]
    short* WloT = (short*)(ws + (size_t)(102u << 20));  // 6 MB
    short* WoT  = (short*)(ws + (size_t)(108u << 20));  // 2 MB [1024][1024]

    // 1) weight transpose+split
    transpose_split_kernel<<<dim3(48, 16), 256, 0, stream>>>(Wqkv, 3 * CEMB, WhiT, WloT);
    transpose_split_kernel<<<dim3(16, 16), 256, 0, stream>>>(Wo, CEMB, WoT, nullptr);

    // 2) V = x @ Wv + bv  (bf16 out)
    gemm_mfma_kernel<1, true, 1><<<dim3(8, 64), 256, 0, stream>>>(
        x, nullptr, WhiT + (size_t)2048 * 1024, nullptr, bqkv + 2048, vbuf, nullptr, CEMB, CEMB);

    // 3) repack V -> Vt
    repack_vt_kernel<<<dim3(32, 16, 4), 256, 0, stream>>>(vbuf, Vt);

    // 4) qk = x @ Wqk + b  -> split hi/lo bf16, q cols pre-scaled (overwrites vbuf)
    gemm_mfma_kernel<3, true, 2><<<dim3(16, 64), 256, 0, stream>>>(
        x, nullptr, WhiT, WloT, bqkv, qkhi, qklo, CEMB, 2048);

    // 5) causal MFMA flash attention -> ctx bf16
    attn_mfma_kernel<<<dim3(512), 256, 0, stream>>>(qkhi, qklo, Vt, ctxb);

    // 6) out = ctx @ Wo + bo  (fp32 out)
    gemm_mfma_kernel<1, false, 0><<<dim3(8, 64), 256, 0, stream>>>(
        nullptr, ctxb, WoT, nullptr, bo, out, nullptr, CEMB, CEMB);
}